// Round 15
// baseline (139.052 us; speedup 1.0000x reference)
//
#include <hip/hip_runtime.h>
#include <math.h>

#define PCAP 512  // per-block LDS positive-pair staging capacity (u32 records)

typedef float f32x4 __attribute__((ext_vector_type(4)));
typedef __attribute__((address_space(3))) unsigned int lds_u32;
typedef __attribute__((address_space(1))) const unsigned int glb_u32;

// ---------------------------------------------------------------------------
// Kernel 1: row normalization (4 rows per block, one per wave) + zero
// unsim/accum/pcur. Output: fp8 e4m3 rows in a PRE-SWIZZLED layout:
// 16B chunk c of row r is stored at chunk (c ^ (r&7)). pass1 then stages
// rows verbatim with async global_load_lds and reads with the same swizzle.
__global__ __launch_bounds__(256) void norm_kernel(
    const float* __restrict__ X, unsigned char* __restrict__ Y8,
    float* __restrict__ unsim, float* __restrict__ accum, float inv_sqrtT) {
  int t = threadIdx.x;
  int w = t >> 6, lane = t & 63;
  int row = blockIdx.x * 4 + w;
  float2 v = ((const float2*)(X + (size_t)row * 128))[lane];
  float s = v.x * v.x + v.y * v.y;
#pragma unroll
  for (int m = 1; m < 64; m <<= 1) s += __shfl_xor(s, m);
  float inv = inv_sqrtT * rsqrtf(fmaxf(s, 1e-24f));
  int packed = __builtin_amdgcn_cvt_pk_fp8_f32(v.x * inv, v.y * inv, 0, false);
  // swizzled byte offset for this lane's 2 bytes (byte = lane*2)
  int chunk = lane >> 3;
  int off = ((chunk ^ (row & 7)) << 4) + ((lane & 7) << 1);
  *(unsigned short*)(Y8 + (size_t)row * 128 + off) =
      (unsigned short)(packed & 0xffff);
  if (t < 4) unsim[blockIdx.x * 4 + t] = 0.f;
  if (blockIdx.x == 0 && t < 8) accum[t] = 0.f;  // accum[0..5] + pcur(6,7)
}

// ---------------------------------------------------------------------------
// Kernel 2: fp8 MFMA similarity pass. Each block handles a 64x128 HALF of
// an upper-triangular 128x128 tile pair (4160 blocks): LDS ~28.7 KB ->
// 4 blocks/CU x 8 waves = 32 waves/CU (hardware max occupancy). Each wave
// owns a 32x32 quadrant (acc[2][2], 16 MFMAs). Staging via async
// global_load_lds (pre-swizzled Y8). Packed u32 positive records.
__global__ __launch_bounds__(512, 8) void pass1_kernel(
    const unsigned char* __restrict__ Y8, const int* __restrict__ lab,
    float* __restrict__ unsim, unsigned* __restrict__ posBuf,
    int* __restrict__ pcur, int nt) {
  __shared__ unsigned char As[64][128];   // chunk c at (c ^ (row&7)) * 16
  __shared__ unsigned char Bs[128][128];
  __shared__ int labR[64], labC[128];
  __shared__ float rsumS[64], csumS[128];
  __shared__ unsigned posS[PCAP];
  __shared__ int posCnt, gbaseS;

  // decode: blockIdx -> (tile pair, half)
  int b2 = blockIdx.x;
  int pb = b2 >> 1, half = b2 & 1;
  float ntf = (float)nt;
  int bi = (int)((2.f * ntf + 1.f -
                  sqrtf((2.f * ntf + 1.f) * (2.f * ntf + 1.f) - 8.f * (float)pb)) *
                 0.5f);
  if (bi < 0) bi = 0;
  while ((bi + 1) * nt - ((bi + 1) * bi) / 2 <= pb) ++bi;
  while (bi * nt - (bi * (bi - 1)) / 2 > pb) --bi;
  int bj = bi + (pb - (bi * nt - (bi * (bi - 1)) / 2));
  const int i0 = bi * 128 + half * 64;  // this half's 64 rows
  const int j0 = bj * 128;              // full 128 cols
  const bool offdiag = (bi != bj);

  const int t = threadIdx.x;
  const int w = t >> 6, lane = t & 63;

  // ---- async staging: A = 512 chunks (1/wave), B = 1024 chunks (2/wave) ----
  {
    const int cA0 = w * 64;  // wave-uniform 16B-chunk index into As
    __builtin_amdgcn_global_load_lds(
        (glb_u32*)(Y8 + (size_t)i0 * 128 + (size_t)(cA0 + lane) * 16),
        (lds_u32*)((unsigned char*)&As[0][0] + cA0 * 16), 16, 0, 0);
#pragma unroll
    for (int k = 0; k < 2; ++k) {
      const int cB0 = w * 64 + k * 512;
      __builtin_amdgcn_global_load_lds(
          (glb_u32*)(Y8 + (size_t)j0 * 128 + (size_t)(cB0 + lane) * 16),
          (lds_u32*)((unsigned char*)&Bs[0][0] + cB0 * 16), 16, 0, 0);
    }
  }
  if (t < 64) {
    labR[t] = lab[i0 + t];
    rsumS[t] = 0.f;
  } else if (t < 192) {
    labC[t - 64] = lab[j0 + t - 64];
    csumS[t - 64] = 0.f;
  }
  if (t == 0) posCnt = 0;
  __syncthreads();  // drains vmcnt (global_load_lds) + lgkmcnt

  const int quad = lane >> 4, l16 = lane & 15;
  const int rbase = (w >> 2) * 32, cbase = (w & 3) * 32;  // 32x32 quadrant
  const int sw = l16 & 7;

  f32x4 acc[2][2] = {};
#pragma unroll
  for (int ks = 0; ks < 4; ++ks) {
    const int ch = ks * 2 + (quad >> 1);
    const int off = ((ch ^ sw) << 4) + ((quad & 1) << 3);
    long af[2], bf[2];
#pragma unroll
    for (int p = 0; p < 2; ++p)
      af[p] = *(const long*)&As[rbase + p * 16 + l16][off];
#pragma unroll
    for (int p = 0; p < 2; ++p)
      bf[p] = *(const long*)&Bs[cbase + p * 16 + l16][off];
#pragma unroll
    for (int pi = 0; pi < 2; ++pi)
#pragma unroll
      for (int pj = 0; pj < 2; ++pj)
        acc[pi][pj] = __builtin_amdgcn_mfma_f32_16x16x32_fp8_fp8(
            af[pi], bf[pj], acc[pi][pj], 0, 0, 0);
  }

  // ---- epilogue ----
  int lr[2][4], lc[2];
#pragma unroll
  for (int pi = 0; pi < 2; ++pi)
#pragma unroll
    for (int r = 0; r < 4; ++r) lr[pi][r] = labR[rbase + pi * 16 + quad * 4 + r];
#pragma unroll
  for (int pj = 0; pj < 2; ++pj) lc[pj] = labC[cbase + pj * 16 + l16];

  float rowp[2][4] = {};
  float colp[2] = {0.f, 0.f};
#pragma unroll
  for (int pi = 0; pi < 2; ++pi)
#pragma unroll
    for (int pj = 0; pj < 2; ++pj)
#pragma unroll
      for (int r = 0; r < 4; ++r) {
        const bool same = (lr[pi][r] == lc[pj]);
        float s = acc[pi][pj][r];
        float e = same ? 0.f : __expf(s);
        rowp[pi][r] += e;
        colp[pj] += e;
        if (same) {  // rare (~1/128): LDS-staged packed append
          const int gi = i0 + rbase + pi * 16 + quad * 4 + r;
          const int gj = j0 + cbase + pj * 16 + l16;
          if (offdiag || (gi != gj)) {
            int nadd = offdiag ? 2 : 1;
            int s0 = atomicAdd(&posCnt, nadd);
            _Float16 hs = (_Float16)s;
            unsigned hb = (unsigned)__builtin_bit_cast(unsigned short, hs);
            unsigned e0 = ((unsigned)gi << 16) | hb;
            if (s0 < PCAP) posS[s0] = e0;
            else posBuf[atomicAdd(pcur, 1)] = e0;
            if (offdiag) {
              unsigned e1 = ((unsigned)gj << 16) | hb;
              if (s0 + 1 < PCAP) posS[s0 + 1] = e1;
              else posBuf[atomicAdd(pcur, 1)] = e1;
            }
          }
        }
      }

  // row sums: 4-shfl reduce over the 16 cols, stage in LDS
#pragma unroll
  for (int pi = 0; pi < 2; ++pi)
#pragma unroll
    for (int r = 0; r < 4; ++r) {
      float v = rowp[pi][r];
      v += __shfl_xor(v, 1);
      v += __shfl_xor(v, 2);
      v += __shfl_xor(v, 4);
      v += __shfl_xor(v, 8);
      if (l16 == 0) atomicAdd(&rsumS[rbase + pi * 16 + quad * 4 + r], v);
    }
  // col sums (mirror band): reduce across quads (32 rows), stage in LDS
#pragma unroll
  for (int pj = 0; pj < 2; ++pj) {
    float v = colp[pj];
    v += __shfl_xor(v, 16);
    v += __shfl_xor(v, 32);
    if (quad == 0) atomicAdd(&csumS[cbase + pj * 16 + l16], v);
  }
  __syncthreads();

  // flush: ONE global atomic per row (and per col if off-diagonal)
  if (t < 64) {
    atomicAdd(&unsim[i0 + t], rsumS[t]);
  } else if (t < 192 && offdiag) {
    atomicAdd(&unsim[j0 + (t - 64)], csumS[t - 64]);
  }
  // flush positive records: one global cursor atomic per block
  int total = posCnt < PCAP ? posCnt : PCAP;
  if (t == 0) gbaseS = atomicAdd(pcur, total);
  __syncthreads();
  for (int e = t; e < total; e += 512) posBuf[gbaseS + e] = posS[e];
}

// ---------------------------------------------------------------------------
// Kernel 3: stream packed positive records: rec = (idx<<16)|fp16(s);
// term = log(exp(s) + unsim[idx]) - s. Finalize fused via last-block-done.
__global__ __launch_bounds__(256) void pass3_kernel(
    const unsigned* __restrict__ posBuf, int* __restrict__ pcur,
    const float* __restrict__ unsim, float* __restrict__ accum,
    float* __restrict__ out) {
  int n = *pcur;
  float local = 0.f;
  int stride = 256 * gridDim.x;
  for (int p = blockIdx.x * 256 + threadIdx.x; p < n; p += stride) {
    unsigned rec = posBuf[p];
    unsigned short hb = (unsigned short)(rec & 0xffffu);
    float s = (float)__builtin_bit_cast(_Float16, hb);
    local += __logf(__expf(s) + unsim[rec >> 16]) - s;
  }
  __shared__ float red[4];
#pragma unroll
  for (int msk = 1; msk < 64; msk <<= 1) local += __shfl_xor(local, msk);
  int lane = threadIdx.x & 63, w = threadIdx.x >> 6;
  if (lane == 0) red[w] = local;
  __syncthreads();
  if (threadIdx.x == 0) {
    atomicAdd(&accum[0], red[0] + red[1] + red[2] + red[3]);
    __threadfence();
    int* done = (int*)&accum[2];
    if (atomicAdd(done, 1) == (int)gridDim.x - 1) {
      float ls = __hip_atomic_load(&accum[0], __ATOMIC_ACQUIRE,
                                   __HIP_MEMORY_SCOPE_AGENT);
      out[0] = ls / (float)n;
    }
  }
}

// ---------------------------------------------------------------------------
extern "C" void kernel_launch(void* const* d_in, const int* in_sizes, int n_in,
                              void* d_out, int out_size, void* d_ws,
                              size_t ws_size, hipStream_t stream) {
  const float* X = (const float*)d_in[0];
  const int* lab = (const int*)d_in[1];
  float* out = (float*)d_out;

  const int N = in_sizes[1];  // 8192; D fixed at 128

  // workspace layout
  unsigned char* Y8 = (unsigned char*)d_ws;       // N*128 fp8 (1 MB)
  float* unsim = (float*)(Y8 + (size_t)N * 128);  // N f32
  float* accum = unsim + N;                       // [0] loss, [2] done ctr
  int* pcur = (int*)(accum + 6);                  // record cursor (+ pad)
  unsigned* posBuf = (unsigned*)(pcur + 2);       // ~524k u32 (2.1 MB)

  const float inv_sqrtT = 2.2360679775f;  // 1/sqrt(0.2)
  norm_kernel<<<N / 4, 256, 0, stream>>>(X, Y8, unsim, accum, inv_sqrtT);

  const int nt = N / 128;              // 64 tiles per dim
  const int nblk = nt * (nt + 1) / 2;  // 2080 upper-tri tile pairs
  pass1_kernel<<<nblk * 2, 512, 0, stream>>>(Y8, lab, unsim, posBuf, pcur, nt);
  pass3_kernel<<<512, 256, 0, stream>>>(posBuf, pcur, unsim, accum, out);
}

// Round 16
// 129.528 us; speedup vs baseline: 1.0735x; 1.0735x over previous
//
#include <hip/hip_runtime.h>
#include <math.h>

#define PCAP 512  // per-block LDS positive-pair staging capacity (u32 records)

typedef float f32x4 __attribute__((ext_vector_type(4)));
typedef __attribute__((address_space(3))) unsigned int lds_u32;
typedef __attribute__((address_space(1))) const unsigned int glb_u32;

// ---------------------------------------------------------------------------
// Kernel 1: row normalization (8 rows per block, 32 lanes per row, float4
// loads) + zero unsim/accum/pcur. Output: fp8 e4m3 rows PRE-SWIZZLED:
// 16B chunk c of row r stored at chunk (c ^ (r&7)); pass1 stages rows
// verbatim with async global_load_lds and reads with the same swizzle.
__global__ __launch_bounds__(256) void norm_kernel(
    const float* __restrict__ X, unsigned char* __restrict__ Y8,
    float* __restrict__ unsim, float* __restrict__ accum, float inv_sqrtT) {
  int t = threadIdx.x;
  int row = blockIdx.x * 8 + (t >> 5);
  int l32 = t & 31;
  float4 v = ((const float4*)(X + (size_t)row * 128))[l32];
  float s = v.x * v.x + v.y * v.y + v.z * v.z + v.w * v.w;
  s += __shfl_xor(s, 1);
  s += __shfl_xor(s, 2);
  s += __shfl_xor(s, 4);
  s += __shfl_xor(s, 8);
  s += __shfl_xor(s, 16);
  float inv = inv_sqrtT * rsqrtf(fmaxf(s, 1e-24f));
  int pk = __builtin_amdgcn_cvt_pk_fp8_f32(v.x * inv, v.y * inv, 0, false);
  pk = __builtin_amdgcn_cvt_pk_fp8_f32(v.z * inv, v.w * inv, pk, true);
  // swizzled byte offset for this lane's 4 bytes (byte = l32*4)
  int chunk = l32 >> 2;
  int off = ((chunk ^ (row & 7)) << 4) + ((l32 & 3) << 2);
  *(unsigned int*)(Y8 + (size_t)row * 128 + off) = (unsigned)pk;
  if (t < 8) unsim[blockIdx.x * 8 + t] = 0.f;
  if (blockIdx.x == 0 && ((t >> 5) == 7) && l32 < 8)
    accum[l32] = 0.f;  // accum[0..5] + pcur(6,7)
}

// ---------------------------------------------------------------------------
// Kernel 2 (R14 verbatim — the measured local optimum): fp8 MFMA similarity
// pass over upper-triangular 128x128 tile pairs. 512-thread blocks, 8 waves
// each owning a 32x64 quadrant (acc[2][4]); 3 blocks/CU x 8 waves = 6
// waves/SIMD. Staging via async global_load_lds (pre-swizzled Y8). Packed
// u32 positive records, LDS-staged; ONE global pcur atomic per block.
// (R5 smaller tile / R15 split tile / R10 fused norm / R9 coop all regressed.)
__global__ __launch_bounds__(512, 6) void pass1_kernel(
    const unsigned char* __restrict__ Y8, const int* __restrict__ lab,
    float* __restrict__ unsim, unsigned* __restrict__ posBuf,
    int* __restrict__ pcur, int nt) {
  __shared__ unsigned char As[128][128];  // chunk c at (c ^ (row&7)) * 16
  __shared__ unsigned char Bs[128][128];
  __shared__ int labR[128], labC[128];
  __shared__ float rsumS[128], csumS[128];
  __shared__ unsigned posS[PCAP];
  __shared__ int posCnt, gbaseS;

  // decode linear block id -> (bi, bj), bi <= bj (triangular)
  int b = blockIdx.x;
  float ntf = (float)nt;
  int bi = (int)((2.f * ntf + 1.f -
                  sqrtf((2.f * ntf + 1.f) * (2.f * ntf + 1.f) - 8.f * (float)b)) *
                 0.5f);
  if (bi < 0) bi = 0;
  while ((bi + 1) * nt - ((bi + 1) * bi) / 2 <= b) ++bi;
  while (bi * nt - (bi * (bi - 1)) / 2 > b) --bi;
  int bj = bi + (b - (bi * nt - (bi * (bi - 1)) / 2));
  const int i0 = bi * 128, j0 = bj * 128;
  const bool offdiag = (bi != bj);

  const int t = threadIdx.x;
  const int w = t >> 6, lane = t & 63;

  // ---- async staging: 2 x (A,B) 1KB segments per wave (8 waves) ----
#pragma unroll
  for (int k = 0; k < 2; ++k) {
    const int c0 = w * 64 + k * 512;  // wave-uniform 16B-chunk index
    const int c = c0 + lane;
    __builtin_amdgcn_global_load_lds(
        (glb_u32*)(Y8 + (size_t)i0 * 128 + (size_t)c * 16),
        (lds_u32*)((unsigned char*)&As[0][0] + c0 * 16), 16, 0, 0);
    __builtin_amdgcn_global_load_lds(
        (glb_u32*)(Y8 + (size_t)j0 * 128 + (size_t)c * 16),
        (lds_u32*)((unsigned char*)&Bs[0][0] + c0 * 16), 16, 0, 0);
  }
  if (t < 128) {
    labR[t] = lab[i0 + t];
    rsumS[t] = 0.f;
  } else if (t < 256) {
    labC[t - 128] = lab[j0 + t - 128];
    csumS[t - 128] = 0.f;
  }
  if (t == 0) posCnt = 0;
  __syncthreads();  // drains vmcnt (global_load_lds) + lgkmcnt

  const int quad = lane >> 4, l16 = lane & 15;
  const int rbase = (w >> 1) * 32, cbase = (w & 1) * 64;  // 32x64 quadrant
  const int sw = l16 & 7;

  f32x4 acc[2][4] = {};
#pragma unroll
  for (int ks = 0; ks < 4; ++ks) {
    const int ch = ks * 2 + (quad >> 1);
    const int off = ((ch ^ sw) << 4) + ((quad & 1) << 3);
    long af[2], bf[4];
#pragma unroll
    for (int p = 0; p < 2; ++p)
      af[p] = *(const long*)&As[rbase + p * 16 + l16][off];
#pragma unroll
    for (int p = 0; p < 4; ++p)
      bf[p] = *(const long*)&Bs[cbase + p * 16 + l16][off];
#pragma unroll
    for (int pi = 0; pi < 2; ++pi)
#pragma unroll
      for (int pj = 0; pj < 4; ++pj)
        acc[pi][pj] = __builtin_amdgcn_mfma_f32_16x16x32_fp8_fp8(
            af[pi], bf[pj], acc[pi][pj], 0, 0, 0);
  }

  // ---- epilogue ----
  int lr[2][4], lc[4];
#pragma unroll
  for (int pi = 0; pi < 2; ++pi)
#pragma unroll
    for (int r = 0; r < 4; ++r) lr[pi][r] = labR[rbase + pi * 16 + quad * 4 + r];
#pragma unroll
  for (int pj = 0; pj < 4; ++pj) lc[pj] = labC[cbase + pj * 16 + l16];

  float rowp[2][4] = {};
  float colp[4] = {0.f, 0.f, 0.f, 0.f};
#pragma unroll
  for (int pi = 0; pi < 2; ++pi)
#pragma unroll
    for (int pj = 0; pj < 4; ++pj)
#pragma unroll
      for (int r = 0; r < 4; ++r) {
        const bool same = (lr[pi][r] == lc[pj]);
        float s = acc[pi][pj][r];
        float e = same ? 0.f : __expf(s);
        rowp[pi][r] += e;
        colp[pj] += e;
        if (same) {  // rare (~1/128): LDS-staged packed append
          const int gi = i0 + rbase + pi * 16 + quad * 4 + r;
          const int gj = j0 + cbase + pj * 16 + l16;
          if (offdiag || (gi != gj)) {
            int nadd = offdiag ? 2 : 1;
            int s0 = atomicAdd(&posCnt, nadd);
            _Float16 hs = (_Float16)s;
            unsigned hb = (unsigned)__builtin_bit_cast(unsigned short, hs);
            unsigned e0 = ((unsigned)gi << 16) | hb;
            if (s0 < PCAP) posS[s0] = e0;
            else posBuf[atomicAdd(pcur, 1)] = e0;
            if (offdiag) {
              unsigned e1 = ((unsigned)gj << 16) | hb;
              if (s0 + 1 < PCAP) posS[s0 + 1] = e1;
              else posBuf[atomicAdd(pcur, 1)] = e1;
            }
          }
        }
      }

  // row sums: 4-shfl reduce over the 16 cols, stage in LDS
#pragma unroll
  for (int pi = 0; pi < 2; ++pi)
#pragma unroll
    for (int r = 0; r < 4; ++r) {
      float v = rowp[pi][r];
      v += __shfl_xor(v, 1);
      v += __shfl_xor(v, 2);
      v += __shfl_xor(v, 4);
      v += __shfl_xor(v, 8);
      if (l16 == 0) atomicAdd(&rsumS[rbase + pi * 16 + quad * 4 + r], v);
    }
  // col sums (mirror band): reduce across quads (32 rows), stage in LDS
#pragma unroll
  for (int pj = 0; pj < 4; ++pj) {
    float v = colp[pj];
    v += __shfl_xor(v, 16);
    v += __shfl_xor(v, 32);
    if (quad == 0) atomicAdd(&csumS[cbase + pj * 16 + l16], v);
  }
  __syncthreads();

  // flush: ONE global atomic per row (and per col if off-diagonal)
  if (t < 128) {
    atomicAdd(&unsim[i0 + t], rsumS[t]);
  } else if (t < 256 && offdiag) {
    atomicAdd(&unsim[j0 + (t - 128)], csumS[t - 128]);
  }
  // flush positive records: one global cursor atomic per block
  int total = posCnt < PCAP ? posCnt : PCAP;
  if (t == 0) gbaseS = atomicAdd(pcur, total);
  __syncthreads();
  for (int e = t; e < total; e += 512) posBuf[gbaseS + e] = posS[e];
}

// ---------------------------------------------------------------------------
// Kernel 3: stream packed positive records: rec = (idx<<16)|fp16(s);
// term = log(exp(s) + unsim[idx]) - s. Finalize fused via last-block-done.
__global__ __launch_bounds__(256) void pass3_kernel(
    const unsigned* __restrict__ posBuf, int* __restrict__ pcur,
    const float* __restrict__ unsim, float* __restrict__ accum,
    float* __restrict__ out) {
  int n = *pcur;
  float local = 0.f;
  int stride = 256 * gridDim.x;
  for (int p = blockIdx.x * 256 + threadIdx.x; p < n; p += stride) {
    unsigned rec = posBuf[p];
    unsigned short hb = (unsigned short)(rec & 0xffffu);
    float s = (float)__builtin_bit_cast(_Float16, hb);
    local += __logf(__expf(s) + unsim[rec >> 16]) - s;
  }
  __shared__ float red[4];
#pragma unroll
  for (int msk = 1; msk < 64; msk <<= 1) local += __shfl_xor(local, msk);
  int lane = threadIdx.x & 63, w = threadIdx.x >> 6;
  if (lane == 0) red[w] = local;
  __syncthreads();
  if (threadIdx.x == 0) {
    atomicAdd(&accum[0], red[0] + red[1] + red[2] + red[3]);
    __threadfence();
    int* done = (int*)&accum[2];
    if (atomicAdd(done, 1) == (int)gridDim.x - 1) {
      float ls = __hip_atomic_load(&accum[0], __ATOMIC_ACQUIRE,
                                   __HIP_MEMORY_SCOPE_AGENT);
      out[0] = ls / (float)n;
    }
  }
}

// ---------------------------------------------------------------------------
extern "C" void kernel_launch(void* const* d_in, const int* in_sizes, int n_in,
                              void* d_out, int out_size, void* d_ws,
                              size_t ws_size, hipStream_t stream) {
  const float* X = (const float*)d_in[0];
  const int* lab = (const int*)d_in[1];
  float* out = (float*)d_out;

  const int N = in_sizes[1];  // 8192; D fixed at 128

  // workspace layout
  unsigned char* Y8 = (unsigned char*)d_ws;       // N*128 fp8 (1 MB)
  float* unsim = (float*)(Y8 + (size_t)N * 128);  // N f32
  float* accum = unsim + N;                       // [0] loss, [2] done ctr
  int* pcur = (int*)(accum + 6);                  // record cursor (+ pad)
  unsigned* posBuf = (unsigned*)(pcur + 2);       // ~524k u32 (2.1 MB)

  const float inv_sqrtT = 2.2360679775f;  // 1/sqrt(0.2)
  norm_kernel<<<N / 8, 256, 0, stream>>>(X, Y8, unsim, accum, inv_sqrtT);

  const int nt = N / 128;              // 64 tiles per dim
  const int nblk = nt * (nt + 1) / 2;  // 2080 upper-tri tile pairs
  pass1_kernel<<<nblk, 512, 0, stream>>>(Y8, lab, unsim, posBuf, pcur, nt);
  pass3_kernel<<<1024, 256, 0, stream>>>(posBuf, pcur, unsim, accum, out);
}